// Round 1
// baseline (948.416 us; speedup 1.0000x reference)
//
#include <hip/hip_runtime.h>

// DiagonalSISOCell: out[v,d,q] = sum_n ns[v,d,n] * C[d,n,q]
//   ns = exp(-delta_v * exp(log_nA[d,n])) * state[v,d,n] + delta_v * x[v,d] * B[d,n]
//   delta_v = softplus(x[v,:] . w_delta + b_delta)
// Memory-bound (~846 MB HBM). Wave = 16 v's; lanes = (vv, qg).
// Phase 1: coalesced state load -> ns into wave-private LDS tile.
// Phase 2: uniform (d,n) loop, broadcast ns (LDS) and C (L1), float4 acc.

constexpr int D = 64;
constexpr int N = 16;
constexpr int VPW = 16;                  // v per wave
constexpr int CD = 8;                    // d-chunk size
constexpr int NCHUNK = D / CD;           // 8 chunks
constexpr int NS_STRIDE = CD * N + 4;    // 132 floats per vv (pad: stride%32==4 -> 2-way reads, free)

__global__ __launch_bounds__(256, 4)
void siso_kernel(const float* __restrict__ x,
                 const float* __restrict__ state,
                 const float* __restrict__ log_nA,
                 const float* __restrict__ Bm,
                 const float* __restrict__ Cm,
                 const float* __restrict__ w_delta,
                 const float* __restrict__ b_delta,
                 float* __restrict__ out,
                 int V)
{
    __shared__ __align__(16) float ns_lds[4][VPW * NS_STRIDE];  // 33792 B -> 4 blocks/CU

    const int tid  = threadIdx.x;
    const int wave = tid >> 6;
    const int lane = tid & 63;
    float* nsw = ns_lds[wave];

    const int vbase = blockIdx.x * (4 * VPW) + wave * VPW;

    // ---------- phase 0: delta for this wave's 16 v's ----------
    // lane = vv0*4 + kk ; each lane dots 16 elements of x[v0,:] with w_delta
    const int vv0 = lane >> 2;   // 0..15
    const int kk  = lane & 3;    // 0..3
    const int v0  = vbase + vv0;
    float z = 0.f;
    if (v0 < V) {
        const float4* xr = (const float4*)(x + (size_t)v0 * D) + kk * 4;
        const float4* wr = (const float4*)(w_delta) + kk * 4;
#pragma unroll
        for (int c = 0; c < 4; ++c) {
            float4 xv = xr[c];
            float4 wv = wr[c];
            z += xv.x * wv.x + xv.y * wv.y + xv.z * wv.z + xv.w * wv.w;
        }
    }
    z += __shfl_xor(z, 1, 64);
    z += __shfl_xor(z, 2, 64);
    z += b_delta[0];
    // stable softplus; z is small here but guard anyway
    const float delta0 = (z > 20.f) ? z : __logf(1.f + __expf(z));
    // lane now holds delta for v = vbase + (lane>>2)

    const int qg = lane & 3;     // phase-2 q-group (q = 4*qg .. 4*qg+3)
    const int vv = lane >> 2;    // phase-2 v index within wave
    const int v2 = vbase + vv;

    for (int dc = 0; dc < NCHUNK; ++dc) {
        const int dbase = dc * CD;

        // ---------- phase 1: ns for d in [dbase, dbase+CD) , 16 v's ----------
        // 2048 floats = 512 float4; lane t, iter j handles float4 f = j*64 + t
#pragma unroll
        for (int j = 0; j < 8; ++j) {
            const int voff   = 2 * j + (lane >> 5);        // 0..15
            const int within = (j * 64 + lane) & 31;       // float4 index inside v's chunk
            const int v      = vbase + voff;
            const int doff   = within >> 2;                // 0..7
            const int d      = dbase + doff;
            const int f4n    = within & 3;                 // n quarter

            float4 s = make_float4(0.f, 0.f, 0.f, 0.f);
            float xv = 0.f;
            if (v < V) {
                s  = ((const float4*)(state + (size_t)v * (D * N) + dbase * N))[within];
                xv = x[(size_t)v * D + d];
            }
            const float4 ga = ((const float4*)log_nA)[d * 4 + f4n];
            const float4 gb = ((const float4*)Bm)[d * 4 + f4n];
            const float dl  = __shfl(delta0, voff * 4, 64);
            const float dx  = dl * xv;
            float4 ns;
            ns.x = __expf(-dl * __expf(ga.x)) * s.x + dx * gb.x;
            ns.y = __expf(-dl * __expf(ga.y)) * s.y + dx * gb.y;
            ns.z = __expf(-dl * __expf(ga.z)) * s.z + dx * gb.z;
            ns.w = __expf(-dl * __expf(ga.w)) * s.w + dx * gb.w;
            *(float4*)(nsw + voff * NS_STRIDE + within * 4) = ns;
        }
        __syncthreads();

        // ---------- phase 2: contraction over n, write out ----------
        if (v2 < V) {
            const float* nsv = nsw + vv * NS_STRIDE;
            for (int doff = 0; doff < CD; ++doff) {
                const int d = dbase + doff;
                const float* Crow = Cm + (size_t)d * (N * N) + qg * 4;  // C[d][n][4qg..]
                const float* nsd  = nsv + doff * N;
                float4 acc = make_float4(0.f, 0.f, 0.f, 0.f);
#pragma unroll
                for (int n = 0; n < N; ++n) {
                    const float  a  = nsd[n];                       // LDS broadcast (16 addrs)
                    const float4 c4 = *(const float4*)(Crow + n * N); // 64B contiguous, L1-hot
                    acc.x += a * c4.x;
                    acc.y += a * c4.y;
                    acc.z += a * c4.z;
                    acc.w += a * c4.w;
                }
                *(float4*)(out + (size_t)v2 * (D * N) + d * N + qg * 4) = acc;
            }
        }
        __syncthreads();
    }
}

extern "C" void kernel_launch(void* const* d_in, const int* in_sizes, int n_in,
                              void* d_out, int out_size, void* d_ws, size_t ws_size,
                              hipStream_t stream) {
    const float* x       = (const float*)d_in[0];
    const float* state   = (const float*)d_in[1];
    const float* log_nA  = (const float*)d_in[2];
    const float* Bm      = (const float*)d_in[3];
    const float* Cm      = (const float*)d_in[4];
    const float* w_delta = (const float*)d_in[5];
    const float* b_delta = (const float*)d_in[6];
    float* out = (float*)d_out;

    const int V = in_sizes[0] / D;                 // 100000
    const int blocks = (V + 4 * VPW - 1) / (4 * VPW);  // 64 v per block

    siso_kernel<<<blocks, 256, 0, stream>>>(x, state, log_nA, Bm, Cm,
                                            w_delta, b_delta, out, V);
}